// Round 12
// baseline (123.153 us; speedup 1.0000x reference)
//
#include <hip/hip_runtime.h>
#include <hip/hip_fp16.h>

#define BATCH 2048
#define NPREP 95   // prep blocks prefixed to kA's grid

typedef _Float16 f16x8 __attribute__((ext_vector_type(8)));
typedef float f32x4 __attribute__((ext_vector_type(4)));

__device__ __forceinline__ float sigmoidf(float v) {
    return 1.0f / (1.0f + __expf(-v));
}

// ---------------------------------------------------------------------------
// Workspace layout (bytes):
//   [0      .. 301056)   W3B  tree B-frags f16 [gi 21][c 14][lane 64][8h]
//                        value for k = c*32 + (lane>>4)*8 + u, f = lane&15,
//                        k decoded in ps3 order: tt=k>>6, qq=(k>>4)&3, nn=k&15
//   [301056 .. 322560)   FCW  f32 [gi 21][o 16][f 16]  (o>=10 -> 0)
//   [322560 .. 38857728) ps3  f16 pooled [gi 21][img 2048][448]
//                        half-offset o = tt*64 + q*16 + n  (pb=(7i+tt)*4+q,
//                        channel n within g; n==15 stored as 0.0)
// ---------------------------------------------------------------------------
#define WS_W3B  0
#define WS_FCW  301056
#define WS_PS   322560
#define PS_G_STRIDE (7u * 2048u * 448u)   // halves per g

// ---------------------------------------------------------------------------
// kA: blocks [0, NPREP) = weight prep (W3B + FCW, consumed only by kBC);
//     blocks [NPREP, NPREP+3072) = conv for ONE (image-pair, g).
// Conv A-frags read directly from 4 shift-replicated f16 copies of each
// 32x36 channel image (taps k=wr*8+wc rows 0..3; 2nd MFMA = row 4).
// LDS: 2 img x 4656 halves = 18,624 B -> 8 blocks/CU = 32 waves/CU (100%).
// ---------------------------------------------------------------------------
__global__ __launch_bounds__(256, 8) void kA_conv_prep(
    const float* __restrict__ x,       // [B][3][32][32]
    const float* __restrict__ conv_w,  // [45][25]
    const float* __restrict__ conv_b,  // [45]
    const float* __restrict__ tree_w,  // [16][15][3][7][7][2][2]
    const float* __restrict__ fc_w,    // [10][336]
    ushort* __restrict__ W3B,
    float* __restrict__ FCW,
    ushort* __restrict__ ps3)          // [21][2048][448] f16
{
    __shared__ __align__(16) ushort xsc[2 * 4656];
    const int tid = threadIdx.x;

    if (blockIdx.x < NPREP) {
        // ================= prep path (no barriers, no LDS use) =============
        int pidx = blockIdx.x * 256 + tid;
        if (pidx < 18816) {                     // W3B: 21*14*64 uint4
            int gi = pidx / 896;
            int rem = pidx - gi * 896;
            int c = rem >> 6, lane2 = rem & 63;
            int f = lane2 & 15, qq = lane2 >> 4;
            int g = gi / 7, i = gi - g * 7;
            ushort h[8];
            #pragma unroll
            for (int u = 0; u < 8; u++) {
                int k = c * 32 + qq * 8 + u;    // 0..447
                int tt = k >> 6;
                int q2 = (k >> 4) & 3;
                int nn = k & 15;
                int u27 = tt * 4 + q2;          // 0..27
                int ki = u27 / 14;
                int pw = u27 - ki * 14;
                int j = pw >> 1, kj = pw & 1;
                float v = 0.f;
                if (nn < 15)
                    v = tree_w[(size_t)f * 8820 + nn * 588 + g * 196 + i * 28
                               + j * 4 + ki * 2 + kj];
                h[u] = __half_as_ushort(__float2half(v));
            }
            *(uint4*)(W3B + (size_t)pidx * 8) = *(uint4*)h;
        } else if (pidx < 24192) {              // FCW: 21*16*16 f32
            int j = pidx - 18816;
            int f = j & 15, o = (j >> 4) & 15, gi = j >> 8;
            FCW[j] = (o < 10) ? fc_w[o * 336 + f * 21 + gi] : 0.f;
        }
        return;
    }

    // ==================== conv path: one (img-pair, g) =====================
    const int blk2 = blockIdx.x - NPREP;
    const int pair = blk2 / 3;
    const int g    = blk2 - pair * 3;
    const int img0 = pair * 2;
    const int lane = tid & 63;
    const int n    = lane & 15;
    const int q    = lane >> 4;
    const int wave = tid >> 6;

    // ---- phase 1: both images' channel g -> f16 copy0 (rows stride 36) ----
    #pragma unroll
    for (int im2 = 0; im2 < 2; im2++) {
        float4 v = ((const float4*)(x + (size_t)(img0 + im2) * 3072 + g * 1024))[tid];
        int row = tid >> 3, col = (tid & 7) * 4;
        __half2 a = __float22half2_rn(make_float2(v.x, v.y));
        __half2 b = __float22half2_rn(make_float2(v.z, v.w));
        uint2 pk;
        pk.x = *(unsigned int*)&a;
        pk.y = *(unsigned int*)&b;
        *(uint2*)(xsc + im2 * 4656 + row * 36 + col) = pk;
    }
    if (tid < 64) {                    // zero cols 32..35 of copy0
        int im2 = tid >> 5, r = tid & 31;
        *(uint2*)(xsc + im2 * 4656 + r * 36 + 32) = make_uint2(0u, 0u);
    }

    // ---- B-frags + bias direct from conv_w (L2-hot) ----
    f16x8 B1 = {0, 0, 0, 0, 0, 0, 0, 0};
    f16x8 B2 = {0, 0, 0, 0, 0, 0, 0, 0};
    float bias = 0.f;
    if (n < 15) {
        const float* wrow = conv_w + (g * 15 + n) * 25;
        #pragma unroll
        for (int u = 0; u < 5; u++) B1[u] = (_Float16)wrow[q * 5 + u];
        if (q == 0) {
            #pragma unroll
            for (int u = 0; u < 5; u++) B2[u] = (_Float16)wrow[20 + u];
        }
        bias = conv_b[g * 15 + n];
    }
    __syncthreads();

    // ---- phase 2: shifted copies s=1..3 for both images (LDS->LDS b64) ----
    for (int t = tid; t < 1728; t += 256) {
        int im2 = t / 864;
        int rem = t - im2 * 864;
        int s = rem / 288 + 1;
        int rem2 = rem - (s - 1) * 288;
        int row = rem2 / 9, g4 = rem2 - row * 9;
        ushort* base = xsc + im2 * 4656;
        ushort* dst = base + s * 1164 + row * 36 + g4 * 4;
        if (g4 == 8) { *(uint2*)dst = make_uint2(0u, 0u); continue; }
        uint2 lo = *(const uint2*)(base + row * 36 + g4 * 4);
        uint2 hi = *(const uint2*)(base + row * 36 + g4 * 4 + 4);
        unsigned int w0 = lo.x, w1 = lo.y, w2 = hi.x, w3 = hi.y;
        unsigned int o0, o1;
        if (s == 1)      { o0 = (w0 >> 16) | (w1 << 16); o1 = (w1 >> 16) | (w2 << 16); }
        else if (s == 2) { o0 = w1;                      o1 = w2; }
        else             { o0 = (w1 >> 16) | (w2 << 16); o1 = (w2 >> 16) | (w3 << 16); }
        *(uint2*)dst = make_uint2(o0, o1);
    }

    // ---- hoisted per-wave tile offsets (img-independent) ----
    const int dr = (n >> 1) & 1, dc = n & 1, n4 = n >> 2;
    const int a2c = 144 - q * 36;      // A1 base -> row r+4
    int aoff[13], svr[13];
    #pragma unroll
    for (int it = 0; it < 13; it++) {
        int t = wave + it * 4;         // it<12 always <49; it==12 only wave 0
        int pb = t * 4 + n4;
        int ph = pb / 14, pw = pb - ph * 14;
        int r = 2 * ph + dr, c = 2 * pw + dc;
        int s = c & 3;
        aoff[it] = s * 1164 + (r + q) * 36 + (c - s);
        int i = t / 7, tt = t - i * 7;
        svr[it] = i * (2048 * 448) + tt * 64 + lane;
    }
    __syncthreads();

    // ---- main: per image, 12 uniform tiles + wave0 tail ----
    ushort* psg = ps3 + (size_t)g * PS_G_STRIDE;
    #pragma unroll
    for (int im2 = 0; im2 < 2; im2++) {
        const ushort* xb = xsc + im2 * 4656;
        const int sb = (img0 + im2) * 448;
        #pragma unroll
        for (int it = 0; it < 12; it++) {
            const ushort* pA = xb + aoff[it];
            union { struct { uint2 a, b; } u; f16x8 v; } A1, A2;
            A1.u.a = *(const uint2*)pA;
            A1.u.b = *(const uint2*)(pA + 4);
            A2.u.a = *(const uint2*)(pA + a2c);
            A2.u.b = *(const uint2*)(pA + a2c + 4);
            f32x4 d = {0.f, 0.f, 0.f, 0.f};
            d = __builtin_amdgcn_mfma_f32_16x16x32_f16(A1.v, B1, d, 0, 0, 0);
            d = __builtin_amdgcn_mfma_f32_16x16x32_f16(A2.v, B2, d, 0, 0, 0);
            float mx = fmaxf(fmaxf(d[0], d[1]), fmaxf(d[2], d[3]));
            float val = (n < 15) ? sigmoidf(mx + bias) : 0.f;
            psg[sb + svr[it]] = __half_as_ushort(__float2half(val));
        }
        if (wave == 0) {               // tile 48
            const ushort* pA = xb + aoff[12];
            union { struct { uint2 a, b; } u; f16x8 v; } A1, A2;
            A1.u.a = *(const uint2*)pA;
            A1.u.b = *(const uint2*)(pA + 4);
            A2.u.a = *(const uint2*)(pA + a2c);
            A2.u.b = *(const uint2*)(pA + a2c + 4);
            f32x4 d = {0.f, 0.f, 0.f, 0.f};
            d = __builtin_amdgcn_mfma_f32_16x16x32_f16(A1.v, B1, d, 0, 0, 0);
            d = __builtin_amdgcn_mfma_f32_16x16x32_f16(A2.v, B2, d, 0, 0, 0);
            float mx = fmaxf(fmaxf(d[0], d[1]), fmaxf(d[2], d[3]));
            float val = (n < 15) ? sigmoidf(mx + bias) : 0.f;
            psg[sb + svr[12]] = __half_as_ushort(__float2half(val));
        }
    }
}

// ---------------------------------------------------------------------------
// kBC: tree einsum (MFMA GEMM over images) + sigmoid + partial FC with
// atomic accumulation into out.  Block = 128 thr, one (gi, 32-img tile).
// Grid (64, 21).  Staging: 56 exact uint4 per image, fully coalesced;
// K = 448 = 14 exact chunks, no zero-fill.
// ---------------------------------------------------------------------------
__global__ __launch_bounds__(128, 3) void kBC_tree_fc(
    const ushort* __restrict__ ps3,    // [21][2048][448] f16
    const ushort* __restrict__ W3B,
    const float* __restrict__ tree_b,  // [336]
    const float* __restrict__ FCW,     // [21][16][16] f32
    const float* __restrict__ fc_b,    // [10]
    float* __restrict__ out)           // [2048][10] (pre-zeroed)
{
    __shared__ __align__(16) ushort im[32 * 456];
    __shared__ __align__(16) ushort tsl[32 * 16];

    const int btile = blockIdx.x;
    const int gi    = blockIdx.y;
    const int img0  = btile * 32;
    const int tid   = threadIdx.x;
    const int lane  = tid & 63;
    const int n     = lane & 15;
    const int q     = lane >> 4;
    const int wave  = tid >> 6;

    // ---- stage 32 images x 56 uint4 (whole 448-half rows) ----
    const uint4* src = (const uint4*)(ps3 + ((size_t)gi * 2048 + img0) * 448);
    #pragma unroll
    for (int it = 0; it < 14; it++) {          // 1792 = 14 * 128 exactly
        int t = tid + it * 128;
        int img = t / 56;
        int o = t - img * 56;
        *(uint4*)(im + img * 456 + o * 8) = src[t];
    }

    // ---- preload 14 B-frags (16 B/lane coalesced, L2-shared) ----
    const f16x8* Wbase = (const f16x8*)W3B + (size_t)gi * 896;
    f16x8 B[14];
    #pragma unroll
    for (int c = 0; c < 14; c++) B[c] = Wbase[c * 64 + lane];
    __syncthreads();

    // ---- 14 chained MFMAs: D[img16 x f16] ----
    f32x4 D = {0.f, 0.f, 0.f, 0.f};
    const ushort* arow = im + (wave * 16 + n) * 456;
    #pragma unroll
    for (int c = 0; c < 14; c++) {
        f16x8 Af = *(const f16x8*)(arow + c * 32 + q * 8);
        D = __builtin_amdgcn_mfma_f32_16x16x32_f16(Af, B[c], D, 0, 0, 0);
    }

    // ---- bias + sigmoid -> ts tile in LDS ([imgLocal 32][f 16] f16) ----
    float bias = tree_b[n * 21 + gi];
    #pragma unroll
    for (int r = 0; r < 4; r++) {
        int imgL = wave * 16 + q * 4 + r;
        tsl[imgL * 16 + n] = __half_as_ushort(__float2half(sigmoidf(D[r] + bias)));
    }
    __syncthreads();

    // ---- partial FC: 320 tasks (img, o); 16-feat dot; atomic add ----
    const float4* Wfc = (const float4*)(FCW + gi * 256);
    for (int t = tid; t < 320; t += 128) {
        int img = t / 10, o = t - (t / 10) * 10;
        const uint4* tp = (const uint4*)(tsl + img * 16);
        uint4 t0 = tp[0], t1 = tp[1];
        const __half2* h = (const __half2*)&t0;
        const __half2* h2 = (const __half2*)&t1;
        float4 w0 = Wfc[o * 4], w1 = Wfc[o * 4 + 1];
        float4 w2 = Wfc[o * 4 + 2], w3 = Wfc[o * 4 + 3];
        float acc = (gi == 0) ? fc_b[o] : 0.f;
        float2 p;
        p = __half22float2(h[0]);  acc = fmaf(p.x, w0.x, acc); acc = fmaf(p.y, w0.y, acc);
        p = __half22float2(h[1]);  acc = fmaf(p.x, w0.z, acc); acc = fmaf(p.y, w0.w, acc);
        p = __half22float2(h[2]);  acc = fmaf(p.x, w1.x, acc); acc = fmaf(p.y, w1.y, acc);
        p = __half22float2(h[3]);  acc = fmaf(p.x, w1.z, acc); acc = fmaf(p.y, w1.w, acc);
        p = __half22float2(h2[0]); acc = fmaf(p.x, w2.x, acc); acc = fmaf(p.y, w2.y, acc);
        p = __half22float2(h2[1]); acc = fmaf(p.x, w2.z, acc); acc = fmaf(p.y, w2.w, acc);
        p = __half22float2(h2[2]); acc = fmaf(p.x, w3.x, acc); acc = fmaf(p.y, w3.y, acc);
        p = __half22float2(h2[3]); acc = fmaf(p.x, w3.z, acc); acc = fmaf(p.y, w3.w, acc);
#if defined(__HIP_PLATFORM_AMD__)
        unsafeAtomicAdd(out + (size_t)(img0 + img) * 10 + o, acc);
#else
        atomicAdd(out + (size_t)(img0 + img) * 10 + o, acc);
#endif
    }
}

extern "C" void kernel_launch(void* const* d_in, const int* in_sizes, int n_in,
                              void* d_out, int out_size, void* d_ws, size_t ws_size,
                              hipStream_t stream) {
    const float* x      = (const float*)d_in[0];
    const float* conv_w = (const float*)d_in[1];
    const float* conv_b = (const float*)d_in[2];
    const float* tree_w = (const float*)d_in[3];
    const float* tree_b = (const float*)d_in[4];
    const float* fc_w   = (const float*)d_in[5];
    const float* fc_b   = (const float*)d_in[6];
    float* out = (float*)d_out;

    ushort* W3B = (ushort*)((char*)d_ws + WS_W3B);
    float*  FCW = (float*)((char*)d_ws + WS_FCW);
    ushort* ps3 = (ushort*)((char*)d_ws + WS_PS);

    hipMemsetAsync(out, 0, (size_t)BATCH * 10 * sizeof(float), stream);
    kA_conv_prep<<<NPREP + 1024 * 3, 256, 0, stream>>>(x, conv_w, conv_b, tree_w,
                                                       fc_w, W3B, FCW, ps3);
    kBC_tree_fc<<<dim3(64, 21), 128, 0, stream>>>(ps3, W3B, tree_b, FCW, fc_b, out);
}

// Round 13
// 115.257 us; speedup vs baseline: 1.0685x; 1.0685x over previous
//
#include <hip/hip_runtime.h>
#include <hip/hip_fp16.h>

#define BATCH 2048

typedef _Float16 f16x8 __attribute__((ext_vector_type(8)));
typedef float f32x4 __attribute__((ext_vector_type(4)));

__device__ __forceinline__ float sigmoidf(float v) {
    return 1.0f / (1.0f + __expf(-v));
}

// ---------------------------------------------------------------------------
// Workspace layout (bytes):
//   [0      .. 301056)  W3B  tree B-frags f16 [gi 21][c 14][lane 64][8h]
//                       value for k = c*32 + (lane>>4)*8 + u, f = lane&15,
//                       k order: k = u27*16 + nn, u27 = ki*14 + pw (j=pw>>1,
//                       kj=pw&1), nn = channel-in-group (nn==15 -> 0)
//   [301056 .. 314496)  FCW2 f32 [g 3][o 10][i 7][f 16]
// ---------------------------------------------------------------------------
#define WS_W3B  0
#define WS_FCW  301056

__global__ __launch_bounds__(256) void k_prep(
    const float* __restrict__ tree_w,
    const float* __restrict__ fc_w,
    ushort* __restrict__ W3B,
    float* __restrict__ FCW2)
{
    int pidx = blockIdx.x * 256 + threadIdx.x;
    if (pidx < 18816) {                     // W3B: 21*14*64 uint4
        int gi = pidx / 896;
        int rem = pidx - gi * 896;
        int c = rem >> 6, lane2 = rem & 63;
        int f = lane2 & 15, qq = lane2 >> 4;
        int g = gi / 7, i = gi - g * 7;
        ushort h[8];
        #pragma unroll
        for (int u = 0; u < 8; u++) {
            int k = c * 32 + qq * 8 + u;    // 0..447
            int tt = k >> 6;
            int q2 = (k >> 4) & 3;
            int nn = k & 15;
            int u27 = tt * 4 + q2;          // 0..27
            int ki = u27 / 14;
            int pw = u27 - ki * 14;
            int j = pw >> 1, kj = pw & 1;
            float v = 0.f;
            if (nn < 15)
                v = tree_w[(size_t)f * 8820 + nn * 588 + g * 196 + i * 28
                           + j * 4 + ki * 2 + kj];
            h[u] = __half_as_ushort(__float2half(v));
        }
        *(uint4*)(W3B + (size_t)pidx * 8) = *(uint4*)h;
    } else if (pidx < 22176) {              // FCW2: 3*10*7*16 f32
        int j = pidx - 18816;
        int f = j & 15;
        int r = j >> 4;
        int i = r % 7;
        int r2 = r / 7;
        int o = r2 % 10;
        int g = r2 / 10;
        FCW2[j] = fc_w[o * 336 + f * 21 + g * 7 + i];
    }
}

// ---------------------------------------------------------------------------
// kF: FULLY fused per (image-pair, g): conv5x5 + bias + sigmoid + maxpool2
//     -> ps in LDS -> tree einsum (7 per-i MFMA GEMMs, M=2 images via
//     lane-parity A replication = LDS broadcast) -> sigmoid -> partial FC
//     with atomic accumulation into out.  Grid 3072 blocks x 256 thr.
// LDS: xsc 2x4656 (18,624 B) + ps 2x3192 (12,768 B) + tsl 448 B = 31,840 B
//   -> 5 blocks/CU.
// ---------------------------------------------------------------------------
__global__ __launch_bounds__(256, 4) void kF_all(
    const float* __restrict__ x,       // [B][3][32][32]
    const float* __restrict__ conv_w,  // [45][25]
    const float* __restrict__ conv_b,  // [45]
    const ushort* __restrict__ W3B,
    const float* __restrict__ FCW2,    // [3][10][7][16] f32
    const float* __restrict__ tree_b,  // [336]
    const float* __restrict__ fc_b,    // [10]
    float* __restrict__ out)           // [2048][10] (pre-zeroed)
{
    __shared__ __align__(16) ushort xsc[2 * 4656];
    __shared__ __align__(16) ushort ps[2 * 3192];   // [im2][i 7][456]
    __shared__ __align__(16) ushort tsl[14 * 16];   // [m=im2*7+i][f]

    const int tid  = threadIdx.x;
    const int blk  = blockIdx.x;
    const int pair = blk / 3;
    const int g    = blk - pair * 3;
    const int img0 = pair * 2;
    const int lane = tid & 63;
    const int n    = lane & 15;
    const int q    = lane >> 4;
    const int wave = tid >> 6;

    // ---- phase 1: both images' channel g -> f16 copy0 (rows stride 36) ----
    #pragma unroll
    for (int im2 = 0; im2 < 2; im2++) {
        float4 v = ((const float4*)(x + (size_t)(img0 + im2) * 3072 + g * 1024))[tid];
        int row = tid >> 3, col = (tid & 7) * 4;
        __half2 a = __float22half2_rn(make_float2(v.x, v.y));
        __half2 b = __float22half2_rn(make_float2(v.z, v.w));
        uint2 pk;
        pk.x = *(unsigned int*)&a;
        pk.y = *(unsigned int*)&b;
        *(uint2*)(xsc + im2 * 4656 + row * 36 + col) = pk;
    }
    if (tid < 64) {                    // zero cols 32..35 of copy0
        int im2 = tid >> 5, r = tid & 31;
        *(uint2*)(xsc + im2 * 4656 + r * 36 + 32) = make_uint2(0u, 0u);
    }

    // ---- conv B-frags + bias direct from conv_w (L2-hot) ----
    f16x8 B1 = {0, 0, 0, 0, 0, 0, 0, 0};
    f16x8 B2 = {0, 0, 0, 0, 0, 0, 0, 0};
    float bias = 0.f;
    if (n < 15) {
        const float* wrow = conv_w + (g * 15 + n) * 25;
        #pragma unroll
        for (int u = 0; u < 5; u++) B1[u] = (_Float16)wrow[q * 5 + u];
        if (q == 0) {
            #pragma unroll
            for (int u = 0; u < 5; u++) B2[u] = (_Float16)wrow[20 + u];
        }
        bias = conv_b[g * 15 + n];
    }
    __syncthreads();

    // ---- phase 2: shifted copies s=1..3 for both images (LDS->LDS b64) ----
    for (int t = tid; t < 1728; t += 256) {
        int im2 = t / 864;
        int rem = t - im2 * 864;
        int s = rem / 288 + 1;
        int rem2 = rem - (s - 1) * 288;
        int row = rem2 / 9, g4 = rem2 - row * 9;
        ushort* base = xsc + im2 * 4656;
        ushort* dst = base + s * 1164 + row * 36 + g4 * 4;
        if (g4 == 8) { *(uint2*)dst = make_uint2(0u, 0u); continue; }
        uint2 lo = *(const uint2*)(base + row * 36 + g4 * 4);
        uint2 hi = *(const uint2*)(base + row * 36 + g4 * 4 + 4);
        unsigned int w0 = lo.x, w1 = lo.y, w2 = hi.x, w3 = hi.y;
        unsigned int o0, o1;
        if (s == 1)      { o0 = (w0 >> 16) | (w1 << 16); o1 = (w1 >> 16) | (w2 << 16); }
        else if (s == 2) { o0 = w1;                      o1 = w2; }
        else             { o0 = (w1 >> 16) | (w2 << 16); o1 = (w2 >> 16) | (w3 << 16); }
        *(uint2*)dst = make_uint2(o0, o1);
    }

    // ---- hoisted per-wave tile offsets (img-independent) ----
    const int dr = (n >> 1) & 1, dc = n & 1, n4 = n >> 2;
    const int a2c = 144 - q * 36;      // A1 base -> row r+4
    int aoff[13], svr[13];
    #pragma unroll
    for (int it = 0; it < 13; it++) {
        int t = wave + it * 4;         // it<12 always <49; it==12 only wave 0
        int pb = t * 4 + n4;
        int ph = pb / 14, pw = pb - ph * 14;
        int r = 2 * ph + dr, c = 2 * pw + dc;
        int s = c & 3;
        aoff[it] = s * 1164 + (r + q) * 36 + (c - s);
        int i = t / 7, tt = t - i * 7;
        svr[it] = i * 456 + tt * 64 + lane;     // LDS ps offset
    }
    __syncthreads();

    // ---- conv main: per image, 12 uniform tiles + wave0 tail -> ps LDS ----
    #pragma unroll
    for (int im2 = 0; im2 < 2; im2++) {
        const ushort* xb = xsc + im2 * 4656;
        ushort* pso = ps + im2 * 3192;
        #pragma unroll
        for (int it = 0; it < 12; it++) {
            const ushort* pA = xb + aoff[it];
            union { struct { uint2 a, b; } u; f16x8 v; } A1, A2;
            A1.u.a = *(const uint2*)pA;
            A1.u.b = *(const uint2*)(pA + 4);
            A2.u.a = *(const uint2*)(pA + a2c);
            A2.u.b = *(const uint2*)(pA + a2c + 4);
            f32x4 d = {0.f, 0.f, 0.f, 0.f};
            d = __builtin_amdgcn_mfma_f32_16x16x32_f16(A1.v, B1, d, 0, 0, 0);
            d = __builtin_amdgcn_mfma_f32_16x16x32_f16(A2.v, B2, d, 0, 0, 0);
            float mx = fmaxf(fmaxf(d[0], d[1]), fmaxf(d[2], d[3]));
            float val = (n < 15) ? sigmoidf(mx + bias) : 0.f;
            pso[svr[it]] = __half_as_ushort(__float2half(val));
        }
        if (wave == 0) {               // tile 48
            const ushort* pA = xb + aoff[12];
            union { struct { uint2 a, b; } u; f16x8 v; } A1, A2;
            A1.u.a = *(const uint2*)pA;
            A1.u.b = *(const uint2*)(pA + 4);
            A2.u.a = *(const uint2*)(pA + a2c);
            A2.u.b = *(const uint2*)(pA + a2c + 4);
            f32x4 d = {0.f, 0.f, 0.f, 0.f};
            d = __builtin_amdgcn_mfma_f32_16x16x32_f16(A1.v, B1, d, 0, 0, 0);
            d = __builtin_amdgcn_mfma_f32_16x16x32_f16(A2.v, B2, d, 0, 0, 0);
            float mx = fmaxf(fmaxf(d[0], d[1]), fmaxf(d[2], d[3]));
            float val = (n < 15) ? sigmoidf(mx + bias) : 0.f;
            pso[svr[12]] = __half_as_ushort(__float2half(val));
        }
    }
    __syncthreads();

    // ---- tree: 7 per-i GEMMs over waves; M=2 (A rows replicated by lane
    //      parity -> LDS same-address broadcast); N=16 f; K=448=14 chunks ----
    for (int ii = wave; ii < 7; ii += 4) {
        const f16x8* Wb = (const f16x8*)W3B + (size_t)(g * 7 + ii) * 896;
        const ushort* ap = ps + (lane & 1) * 3192 + ii * 456;
        f32x4 D = {0.f, 0.f, 0.f, 0.f};
        #pragma unroll
        for (int c = 0; c < 14; c++) {
            f16x8 Af = *(const f16x8*)(ap + c * 32 + q * 8);
            f16x8 Bf = Wb[c * 64 + lane];
            D = __builtin_amdgcn_mfma_f32_16x16x32_f16(Af, Bf, D, 0, 0, 0);
        }
        if (q == 0) {                  // rows 0,1 = images 0,1
            float tb = tree_b[n * 21 + g * 7 + ii];
            tsl[(0 * 7 + ii) * 16 + n] =
                __half_as_ushort(__float2half(sigmoidf(D[0] + tb)));
            tsl[(1 * 7 + ii) * 16 + n] =
                __half_as_ushort(__float2half(sigmoidf(D[1] + tb)));
        }
    }
    __syncthreads();

    // ---- partial FC: 20 lanes of wave 0, (im2, o); atomic add ----
    if (wave == 0 && lane < 20) {
        int im2 = lane / 10, o = lane - (lane / 10) * 10;
        const __half2* tp = (const __half2*)(tsl + im2 * 7 * 16);
        const float4* wp = (const float4*)(FCW2 + (size_t)(g * 10 + o) * 112);
        float acc = (g == 0) ? fc_b[o] : 0.f;
        #pragma unroll
        for (int jj = 0; jj < 28; jj++) {
            float4 w4 = wp[jj];
            float2 p0 = __half22float2(tp[2 * jj]);
            float2 p1 = __half22float2(tp[2 * jj + 1]);
            acc = fmaf(p0.x, w4.x, acc);
            acc = fmaf(p0.y, w4.y, acc);
            acc = fmaf(p1.x, w4.z, acc);
            acc = fmaf(p1.y, w4.w, acc);
        }
#if defined(__HIP_PLATFORM_AMD__)
        unsafeAtomicAdd(out + (size_t)(img0 + im2) * 10 + o, acc);
#else
        atomicAdd(out + (size_t)(img0 + im2) * 10 + o, acc);
#endif
    }
}

extern "C" void kernel_launch(void* const* d_in, const int* in_sizes, int n_in,
                              void* d_out, int out_size, void* d_ws, size_t ws_size,
                              hipStream_t stream) {
    const float* x      = (const float*)d_in[0];
    const float* conv_w = (const float*)d_in[1];
    const float* conv_b = (const float*)d_in[2];
    const float* tree_w = (const float*)d_in[3];
    const float* tree_b = (const float*)d_in[4];
    const float* fc_w   = (const float*)d_in[5];
    const float* fc_b   = (const float*)d_in[6];
    float* out = (float*)d_out;

    ushort* W3B  = (ushort*)((char*)d_ws + WS_W3B);
    float*  FCW2 = (float*)((char*)d_ws + WS_FCW);

    hipMemsetAsync(out, 0, (size_t)BATCH * 10 * sizeof(float), stream);
    k_prep<<<87, 256, 0, stream>>>(tree_w, fc_w, W3B, FCW2);
    kF_all<<<1024 * 3, 256, 0, stream>>>(x, conv_w, conv_b, W3B, FCW2,
                                         tree_b, fc_b, out);
}

// Round 14
// 114.514 us; speedup vs baseline: 1.0754x; 1.0065x over previous
//
#include <hip/hip_runtime.h>
#include <hip/hip_fp16.h>

#define BATCH 2048

typedef _Float16 f16x8 __attribute__((ext_vector_type(8)));
typedef float f32x4 __attribute__((ext_vector_type(4)));

__device__ __forceinline__ float sigmoidf(float v) {
    return 1.0f / (1.0f + __expf(-v));
}

// ---------------------------------------------------------------------------
// Workspace layout (bytes):
//   [0      .. 301056)  W3B  tree B-frags f16 [gi 21][c 14][lane 64][8h]
//                       value for k = c*32 + (lane>>4)*8 + u, f = lane&15,
//                       k order: k = u27*16 + nn, u27 = tt*4+q2 = ki*14 + pw
//                       (j=pw>>1, kj=pw&1), nn = channel-in-group (15 -> 0)
//   [301056 .. 314496)  FCW2 f32 [g 3][o 10][i 7][f 16]
// ---------------------------------------------------------------------------
#define WS_W3B  0
#define WS_FCW  301056

__global__ __launch_bounds__(256) void k_prep(
    const float* __restrict__ tree_w,
    const float* __restrict__ fc_w,
    ushort* __restrict__ W3B,
    float* __restrict__ FCW2)
{
    int pidx = blockIdx.x * 256 + threadIdx.x;
    if (pidx < 18816) {                     // W3B: 21*14*64 uint4
        int gi = pidx / 896;
        int rem = pidx - gi * 896;
        int c = rem >> 6, lane2 = rem & 63;
        int f = lane2 & 15, qq = lane2 >> 4;
        int g = gi / 7, i = gi - g * 7;
        ushort h[8];
        #pragma unroll
        for (int u = 0; u < 8; u++) {
            int k = c * 32 + qq * 8 + u;    // 0..447
            int tt = k >> 6;
            int q2 = (k >> 4) & 3;
            int nn = k & 15;
            int u27 = tt * 4 + q2;          // 0..27
            int ki = u27 / 14;
            int pw = u27 - ki * 14;
            int j = pw >> 1, kj = pw & 1;
            float v = 0.f;
            if (nn < 15)
                v = tree_w[(size_t)f * 8820 + nn * 588 + g * 196 + i * 28
                           + j * 4 + ki * 2 + kj];
            h[u] = __half_as_ushort(__float2half(v));
        }
        *(uint4*)(W3B + (size_t)pidx * 8) = *(uint4*)h;
    } else if (pidx < 22176) {              // FCW2: 3*10*7*16 f32
        int j = pidx - 18816;
        int f = j & 15;
        int r = j >> 4;
        int i = r % 7;
        int r2 = r / 7;
        int o = r2 % 10;
        int g = r2 / 10;
        FCW2[j] = fc_w[o * 336 + f * 21 + g * 7 + i];
    }
}

// ---------------------------------------------------------------------------
// kF: FULLY fused per (image-pair, g): conv5x5 + bias + sigmoid + maxpool2
//     -> ps in LDS -> tree einsum (7 per-i MFMA GEMMs, M=2 images via
//     lane-parity A replication) -> sigmoid -> partial FC atomically into out.
// Tree phase: 14 B-frags preloaded to a VGPR array (batched global loads,
// single vmcnt wait) + even/odd split accumulators to halve MFMA dep chain.
// LDS: xsc 2x4656 (18,624 B) + ps 2x3192 (12,768 B) + tsl 448 B = 31,840 B.
// ---------------------------------------------------------------------------
__global__ __launch_bounds__(256, 4) void kF_all(
    const float* __restrict__ x,       // [B][3][32][32]
    const float* __restrict__ conv_w,  // [45][25]
    const float* __restrict__ conv_b,  // [45]
    const ushort* __restrict__ W3B,
    const float* __restrict__ FCW2,    // [3][10][7][16] f32
    const float* __restrict__ tree_b,  // [336]
    const float* __restrict__ fc_b,    // [10]
    float* __restrict__ out)           // [2048][10] (pre-zeroed)
{
    __shared__ __align__(16) ushort xsc[2 * 4656];
    __shared__ __align__(16) ushort ps[2 * 3192];   // [im2][i 7][456]
    __shared__ __align__(16) ushort tsl[14 * 16];   // [m=im2*7+i][f]

    const int tid  = threadIdx.x;
    const int blk  = blockIdx.x;
    const int pair = blk / 3;
    const int g    = blk - pair * 3;
    const int img0 = pair * 2;
    const int lane = tid & 63;
    const int n    = lane & 15;
    const int q    = lane >> 4;
    const int wave = tid >> 6;

    // ---- phase 1: both images' channel g -> f16 copy0 (rows stride 36) ----
    #pragma unroll
    for (int im2 = 0; im2 < 2; im2++) {
        float4 v = ((const float4*)(x + (size_t)(img0 + im2) * 3072 + g * 1024))[tid];
        int row = tid >> 3, col = (tid & 7) * 4;
        __half2 a = __float22half2_rn(make_float2(v.x, v.y));
        __half2 b = __float22half2_rn(make_float2(v.z, v.w));
        uint2 pk;
        pk.x = *(unsigned int*)&a;
        pk.y = *(unsigned int*)&b;
        *(uint2*)(xsc + im2 * 4656 + row * 36 + col) = pk;
    }
    if (tid < 64) {                    // zero cols 32..35 of copy0
        int im2 = tid >> 5, r = tid & 31;
        *(uint2*)(xsc + im2 * 4656 + r * 36 + 32) = make_uint2(0u, 0u);
    }

    // ---- conv B-frags + bias direct from conv_w (L2-hot) ----
    f16x8 B1 = {0, 0, 0, 0, 0, 0, 0, 0};
    f16x8 B2 = {0, 0, 0, 0, 0, 0, 0, 0};
    float bias = 0.f;
    if (n < 15) {
        const float* wrow = conv_w + (g * 15 + n) * 25;
        #pragma unroll
        for (int u = 0; u < 5; u++) B1[u] = (_Float16)wrow[q * 5 + u];
        if (q == 0) {
            #pragma unroll
            for (int u = 0; u < 5; u++) B2[u] = (_Float16)wrow[20 + u];
        }
        bias = conv_b[g * 15 + n];
    }
    __syncthreads();

    // ---- phase 2: shifted copies s=1..3 for both images (LDS->LDS b64) ----
    for (int t = tid; t < 1728; t += 256) {
        int im2 = t / 864;
        int rem = t - im2 * 864;
        int s = rem / 288 + 1;
        int rem2 = rem - (s - 1) * 288;
        int row = rem2 / 9, g4 = rem2 - row * 9;
        ushort* base = xsc + im2 * 4656;
        ushort* dst = base + s * 1164 + row * 36 + g4 * 4;
        if (g4 == 8) { *(uint2*)dst = make_uint2(0u, 0u); continue; }
        uint2 lo = *(const uint2*)(base + row * 36 + g4 * 4);
        uint2 hi = *(const uint2*)(base + row * 36 + g4 * 4 + 4);
        unsigned int w0 = lo.x, w1 = lo.y, w2 = hi.x, w3 = hi.y;
        unsigned int o0, o1;
        if (s == 1)      { o0 = (w0 >> 16) | (w1 << 16); o1 = (w1 >> 16) | (w2 << 16); }
        else if (s == 2) { o0 = w1;                      o1 = w2; }
        else             { o0 = (w1 >> 16) | (w2 << 16); o1 = (w2 >> 16) | (w3 << 16); }
        *(uint2*)dst = make_uint2(o0, o1);
    }

    // ---- hoisted per-wave tile offsets (img-independent) ----
    const int dr = (n >> 1) & 1, dc = n & 1, n4 = n >> 2;
    const int a2c = 144 - q * 36;      // A1 base -> row r+4
    int aoff[13], svr[13];
    #pragma unroll
    for (int it = 0; it < 13; it++) {
        int t = wave + it * 4;         // it<12 always <49; it==12 only wave 0
        int pb = t * 4 + n4;
        int ph = pb / 14, pw = pb - ph * 14;
        int r = 2 * ph + dr, c = 2 * pw + dc;
        int s = c & 3;
        aoff[it] = s * 1164 + (r + q) * 36 + (c - s);
        int i = t / 7, tt = t - i * 7;
        svr[it] = i * 456 + tt * 64 + lane;     // LDS ps offset
    }
    __syncthreads();

    // ---- conv main: per image, 12 uniform tiles + wave0 tail -> ps LDS ----
    #pragma unroll
    for (int im2 = 0; im2 < 2; im2++) {
        const ushort* xb = xsc + im2 * 4656;
        ushort* pso = ps + im2 * 3192;
        #pragma unroll
        for (int it = 0; it < 12; it++) {
            const ushort* pA = xb + aoff[it];
            union { struct { uint2 a, b; } u; f16x8 v; } A1, A2;
            A1.u.a = *(const uint2*)pA;
            A1.u.b = *(const uint2*)(pA + 4);
            A2.u.a = *(const uint2*)(pA + a2c);
            A2.u.b = *(const uint2*)(pA + a2c + 4);
            f32x4 d = {0.f, 0.f, 0.f, 0.f};
            d = __builtin_amdgcn_mfma_f32_16x16x32_f16(A1.v, B1, d, 0, 0, 0);
            d = __builtin_amdgcn_mfma_f32_16x16x32_f16(A2.v, B2, d, 0, 0, 0);
            float mx = fmaxf(fmaxf(d[0], d[1]), fmaxf(d[2], d[3]));
            float val = (n < 15) ? sigmoidf(mx + bias) : 0.f;
            pso[svr[it]] = __half_as_ushort(__float2half(val));
        }
        if (wave == 0) {               // tile 48
            const ushort* pA = xb + aoff[12];
            union { struct { uint2 a, b; } u; f16x8 v; } A1, A2;
            A1.u.a = *(const uint2*)pA;
            A1.u.b = *(const uint2*)(pA + 4);
            A2.u.a = *(const uint2*)(pA + a2c);
            A2.u.b = *(const uint2*)(pA + a2c + 4);
            f32x4 d = {0.f, 0.f, 0.f, 0.f};
            d = __builtin_amdgcn_mfma_f32_16x16x32_f16(A1.v, B1, d, 0, 0, 0);
            d = __builtin_amdgcn_mfma_f32_16x16x32_f16(A2.v, B2, d, 0, 0, 0);
            float mx = fmaxf(fmaxf(d[0], d[1]), fmaxf(d[2], d[3]));
            float val = (n < 15) ? sigmoidf(mx + bias) : 0.f;
            pso[svr[12]] = __half_as_ushort(__float2half(val));
        }
    }
    __syncthreads();

    // ---- tree: 7 per-i GEMMs over waves; M=2 via lane-parity broadcast.
    //      B-frags preloaded to VGPR array (one batched vmcnt wait);
    //      even/odd accumulator split halves the MFMA dependency chain. ----
    for (int ii = wave; ii < 7; ii += 4) {
        const f16x8* Wb = (const f16x8*)W3B + (size_t)(g * 7 + ii) * 896;
        const ushort* ap = ps + (lane & 1) * 3192 + ii * 456;
        f16x8 Bf[14];
        #pragma unroll
        for (int c = 0; c < 14; c++) Bf[c] = Wb[c * 64 + lane];
        f32x4 D0 = {0.f, 0.f, 0.f, 0.f};
        f32x4 D1 = {0.f, 0.f, 0.f, 0.f};
        #pragma unroll
        for (int c = 0; c < 7; c++) {
            f16x8 Ae = *(const f16x8*)(ap + (2 * c) * 32 + q * 8);
            D0 = __builtin_amdgcn_mfma_f32_16x16x32_f16(Ae, Bf[2 * c], D0, 0, 0, 0);
            f16x8 Ao = *(const f16x8*)(ap + (2 * c + 1) * 32 + q * 8);
            D1 = __builtin_amdgcn_mfma_f32_16x16x32_f16(Ao, Bf[2 * c + 1], D1, 0, 0, 0);
        }
        if (q == 0) {                  // rows 0,1 = images 0,1
            float tb = tree_b[n * 21 + g * 7 + ii];
            float t0 = (D0[0] + D1[0]) + tb;
            float t1 = (D0[1] + D1[1]) + tb;
            tsl[(0 * 7 + ii) * 16 + n] = __half_as_ushort(__float2half(sigmoidf(t0)));
            tsl[(1 * 7 + ii) * 16 + n] = __half_as_ushort(__float2half(sigmoidf(t1)));
        }
    }
    __syncthreads();

    // ---- partial FC: 20 lanes of wave 0, (im2, o); atomic add ----
    if (wave == 0 && lane < 20) {
        int im2 = lane / 10, o = lane - (lane / 10) * 10;
        const __half2* tp = (const __half2*)(tsl + im2 * 7 * 16);
        const float4* wp = (const float4*)(FCW2 + (size_t)(g * 10 + o) * 112);
        float acc = (g == 0) ? fc_b[o] : 0.f;
        #pragma unroll
        for (int jj = 0; jj < 28; jj++) {
            float4 w4 = wp[jj];
            float2 p0 = __half22float2(tp[2 * jj]);
            float2 p1 = __half22float2(tp[2 * jj + 1]);
            acc = fmaf(p0.x, w4.x, acc);
            acc = fmaf(p0.y, w4.y, acc);
            acc = fmaf(p1.x, w4.z, acc);
            acc = fmaf(p1.y, w4.w, acc);
        }
#if defined(__HIP_PLATFORM_AMD__)
        unsafeAtomicAdd(out + (size_t)(img0 + im2) * 10 + o, acc);
#else
        atomicAdd(out + (size_t)(img0 + im2) * 10 + o, acc);
#endif
    }
}

extern "C" void kernel_launch(void* const* d_in, const int* in_sizes, int n_in,
                              void* d_out, int out_size, void* d_ws, size_t ws_size,
                              hipStream_t stream) {
    const float* x      = (const float*)d_in[0];
    const float* conv_w = (const float*)d_in[1];
    const float* conv_b = (const float*)d_in[2];
    const float* tree_w = (const float*)d_in[3];
    const float* tree_b = (const float*)d_in[4];
    const float* fc_w   = (const float*)d_in[5];
    const float* fc_b   = (const float*)d_in[6];
    float* out = (float*)d_out;

    ushort* W3B  = (ushort*)((char*)d_ws + WS_W3B);
    float*  FCW2 = (float*)((char*)d_ws + WS_FCW);

    hipMemsetAsync(out, 0, (size_t)BATCH * 10 * sizeof(float), stream);
    k_prep<<<87, 256, 0, stream>>>(tree_w, fc_w, W3B, FCW2);
    kF_all<<<1024 * 3, 256, 0, stream>>>(x, conv_w, conv_b, W3B, FCW2,
                                         tree_b, fc_b, out);
}